// Round 9
// baseline (2348.484 us; speedup 1.0000x reference)
//
#include <hip/hip_runtime.h>
#include <hip/hip_bf16.h>
#include <stdint.h>

// 2-layer LSTM, B=1024 T=80 E=100 U=512, bf16 MFMA path.
// R1: layer2(t-1) || layer1(t) software pipeline (81 launches).
// R3/R8: pipeline-depth & register read-ahead: neutral -> not latency-bound.
// R4: 128x128 z-tile -> 1778us (bytes-bound confirmed: time tracks staged bytes).
// R5-R7: persistence attempts regressed (fence/inv semantics); abandoned.
// R9: BK=64, half the barriers: neutral -> not sync-bound. Arithmetic: 8MB staged
//     per k-step at ~5.3TB/s = 1.3us/step x16 = measured 20us -> staging-rate-bound.
// R10: 2-D XCD partition. Old swizzle gave each XCD all 8 bm -> ~7MB working set
//     thrashing its 4MiB L2 -> L3-rate staging. New decode: XCD x = 4bm x 4g x both
//     roles (32 blocks): resident set ~3.3MB < 4MiB -> within-launch A/B re-reads
//     become XCD-local L2 hits; only ~3.3MB/XCD compulsory from L3 per launch.
//     xcd=blockIdx&7 (round-robin mapping), gq=xcd&3, bmq=xcd>>2; bijective.
//     Edge launches (grid 128) use role-free decode via gridDim.x check.

#define B_ 1024
#define T_ 80

using bf16 = __hip_bfloat16;
typedef __attribute__((ext_vector_type(8))) short short8;
typedef __attribute__((ext_vector_type(4))) float f32x4;
typedef __attribute__((ext_vector_type(8))) unsigned short ushort8v;

__device__ __forceinline__ float sigf(float x) { return 1.f / (1.f + __expf(-x)); }
__device__ __forceinline__ float tanh_f(float x) { return 2.f / (1.f + __expf(-2.f * x)) - 1.f; }

typedef const __attribute__((address_space(1))) void* gp1_t;
typedef __attribute__((address_space(3))) void* lp3_t;
__device__ __forceinline__ void llds16(const void* g, void* l) {
  // per-lane global gather -> LDS wave-uniform base + lane*16
  __builtin_amdgcn_global_load_lds((gp1_t)g, (lp3_t)l, 16, 0, 0);
}

// XP[t][b][e] (e padded to 128 with zeros), bf16. Vectorized: thread = 8 elems.
__global__ void embed_kernel(const int* __restrict__ tokens, const float* __restrict__ emb,
                             bf16* __restrict__ XP) {
  int idx = blockIdx.x * 256 + threadIdx.x;  // over T_*B_*16
  int j = idx & 15;                          // e0 = j*8
  int bt = idx >> 4;
  int b = bt & (B_ - 1);
  int t = bt >> 10;
  if (t >= T_) return;
  int tok = tokens[b * T_ + t];
  int e0 = j * 8;
  float v[8];
  if (e0 + 8 <= 100) {
    *(float4*)(v) = *(const float4*)(emb + (size_t)tok * 100 + e0);
    *(float4*)(v + 4) = *(const float4*)(emb + (size_t)tok * 100 + e0 + 4);
  } else if (e0 < 100) {  // e0 == 96: 4 real + 4 zero
    *(float4*)(v) = *(const float4*)(emb + (size_t)tok * 100 + e0);
    v[4] = v[5] = v[6] = v[7] = 0.f;
  } else {
#pragma unroll
    for (int k = 0; k < 8; ++k) v[k] = 0.f;
  }
  ushort8v o;
#pragma unroll
  for (int k = 0; k < 8; ++k) {
    bf16 hb = __float2bfloat16(v[k]);
    o[k] = *(unsigned short*)&hb;
  }
  *(ushort8v*)(XP + (size_t)bt * 128 + e0) = o;
}

// W [Kreal][2048] fp32 -> WT [2048][Kp] bf16, coalesced both ways via 32x32 LDS tile
__global__ void transpose_kernel(const float* __restrict__ W, bf16* __restrict__ WT,
                                 int Kreal, int Kp) {
  __shared__ float tile[32][33];
  int tn = blockIdx.x * 32;
  int tk = blockIdx.y * 32;
  int lx = threadIdx.x & 31;
  int ly = threadIdx.x >> 5;  // 8
#pragma unroll
  for (int r = ly; r < 32; r += 8) {
    int k = tk + r;
    tile[r][lx] = (k < Kreal) ? W[(size_t)k * 2048 + tn + lx] : 0.f;
  }
  __syncthreads();
#pragma unroll
  for (int r = ly; r < 32; r += 8) {
    WT[(size_t)(tn + r) * Kp + tk + lx] = __float2bfloat16(tile[lx][r]);
  }
}

struct CellParams {
  const bf16* A0; const bf16* B0;
  const bf16* A1; const bf16* B1;
  int lda0, ldb0, nkt0, lda1, ldb1, nkt1;  // nkt in units of BK=64
  const float* bias; float* C; bf16* H;
};

// z = A0@B0^T-seg + A1@B1^T-seg + bias; gates i,f,g,o; C fp32 in-place; H bf16 out.
// Block tile 128 rows x 32 units (128 z-cols). 512 threads = 8 waves 2(m)x4(n);
// wave = 4x2 16x16 frags. BK=64: 4 llds16/wave/stage; LDS ring 4x32KB = 128KB.
// Tile decode (R10): xcd = blockIdx&7 -> XCD x owns {g in [ (x&3)*4, +4 ), bm in
// [ (x>>2)*4, +4 ), both roles} = 32 blocks; ~3.3MB working set fits 4MiB L2.
// grid 256: j=blockIdx>>3: role=j&1, gl=(j>>1)&3, bml=(j>>3)&3.
// grid 128 (edge launches, p0==p1): role=0, gl=j&3, bml=(j>>2)&3. Both bijective.
// K-loop: wait vmcnt(8) (2 stages in flight), barrier, stage(kt+3), 12 frag reads,
// 16 MFMA. Epilogue: single pass via z[128][132] f32 (68KB reuses ring).
__global__ __launch_bounds__(512, 1) void cell_kernel(CellParams p0, CellParams p1) {
  __shared__ alignas(16) char smem[131072];
  const int xcd = blockIdx.x & 7;
  const int j = blockIdx.x >> 3;
  const int gq = xcd & 3, bmq = xcd >> 2;
  int role, gl, bml;
  if (gridDim.x == 256) { role = j & 1; gl = (j >> 1) & 3; bml = (j >> 3) & 3; }
  else                  { role = 0;     gl = j & 3;        bml = (j >> 2) & 3; }
  const CellParams& p = role ? p1 : p0;
  const int g = gq * 4 + gl;    // unit-group 0..15
  const int bm = bmq * 4 + bml; // 128-row tile 0..7
  const int u0 = g * 32;        // unit offset
  const int tid = threadIdx.x;
  const int w = tid >> 6, l = tid & 63, q = l >> 4, m = l & 15;
  const int wm = w >> 2, wn = w & 3;

  // staging rows: wave w stages A rows bm*128+w*16+m; B n-rows (w>>1)*512+u0+(w&1)*16+m
  const bf16* arow0 = p.A0 + (size_t)(bm * 128 + w * 16 + m) * p.lda0;
  const bf16* brow0 = p.B0 + (size_t)((w >> 1) * 512 + u0 + (w & 1) * 16 + m) * p.ldb0;
  const bf16* arow1 = p.A1 + (size_t)(bm * 128 + w * 16 + m) * p.lda1;
  const bf16* brow1 = p.B1 + (size_t)((w >> 1) * 512 + u0 + (w & 1) * 16 + m) * p.ldb1;

  auto stage = [&](int kt, int buf) {
    const bf16 *ga, *gb;
    if (kt < p.nkt0) { int k0 = kt * 64 + q * 8; ga = arow0 + k0; gb = brow0 + k0; }
    else { int k0 = (kt - p.nkt0) * 64 + q * 8; ga = arow1 + k0; gb = brow1 + k0; }
    char* ab = smem + buf * 32768 + w * 2048;
    llds16(ga, ab);                    // A s=0 (k 0..31 of this BK)
    llds16(ga + 32, ab + 1024);        // A s=1 (k 32..63)
    llds16(gb, ab + 16384);            // B s=0
    llds16(gb + 32, ab + 16384 + 1024);// B s=1
  };

  f32x4 acc[4][2];
#pragma unroll
  for (int mi = 0; mi < 4; ++mi)
#pragma unroll
    for (int nj = 0; nj < 2; ++nj) acc[mi][nj] = (f32x4){0.f, 0.f, 0.f, 0.f};

  const int fbase = q * 256 + m * 16;
  const int total = p.nkt0 + p.nkt1;  // 10 (layer1) or 16 (layer2)

  stage(0, 0);
  stage(1, 1);
  stage(2, 2);
  for (int kt = 0; kt < total; ++kt) {
    const int rem = total - 1 - kt;
    if (rem >= 2)      asm volatile("s_waitcnt vmcnt(8)" ::: "memory");  // stage kt landed
    else if (rem == 1) asm volatile("s_waitcnt vmcnt(4)" ::: "memory");
    else               asm volatile("s_waitcnt vmcnt(0)" ::: "memory");
    __builtin_amdgcn_s_barrier();       // ALL waves' stage(kt) landed
    __builtin_amdgcn_sched_barrier(0);  // keep ds_reads below the barrier
    if (kt + 3 < total) stage(kt + 3, (kt + 3) & 3);
    const int cb = (kt & 3) * 32768;
    short8 a0[4], b0[2], a1[4], b1[2];
#pragma unroll
    for (int mi = 0; mi < 4; ++mi)
      a0[mi] = *(const short8*)(smem + cb + (wm * 4 + mi) * 2048 + fbase);
#pragma unroll
    for (int nj = 0; nj < 2; ++nj)
      b0[nj] = *(const short8*)(smem + cb + 16384 + (wn * 2 + nj) * 2048 + fbase);
#pragma unroll
    for (int mi = 0; mi < 4; ++mi)
      a1[mi] = *(const short8*)(smem + cb + (wm * 4 + mi) * 2048 + 1024 + fbase);
#pragma unroll
    for (int nj = 0; nj < 2; ++nj)
      b1[nj] = *(const short8*)(smem + cb + 16384 + (wn * 2 + nj) * 2048 + 1024 + fbase);
#pragma unroll
    for (int mi = 0; mi < 4; ++mi)
#pragma unroll
      for (int nj = 0; nj < 2; ++nj)
        acc[mi][nj] = __builtin_amdgcn_mfma_f32_16x16x32_bf16(a0[mi], b0[nj], acc[mi][nj], 0, 0, 0);
#pragma unroll
    for (int mi = 0; mi < 4; ++mi)
#pragma unroll
      for (int nj = 0; nj < 2; ++nj)
        acc[mi][nj] = __builtin_amdgcn_mfma_f32_16x16x32_bf16(a1[mi], b1[nj], acc[mi][nj], 0, 0, 0);
  }

  __syncthreads();  // all frag reads done -> safe to overwrite ring with z
  float* zs = (float*)smem;  // [128][132] f32 = 67.6 KB
#pragma unroll
  for (int mi = 0; mi < 4; ++mi)
#pragma unroll
    for (int nj = 0; nj < 2; ++nj)
#pragma unroll
      for (int r = 0; r < 4; ++r)
        zs[(wm * 64 + mi * 16 + q * 4 + r) * 132 + wn * 32 + nj * 16 + m] = acc[mi][nj][r];
  __syncthreads();

  // one thread per (row, 8-unit chunk): 512 threads = 128 rows x 4 chunks
  const int erow = tid >> 2;
  const int ub8 = (tid & 3) * 8;
  const int gu0 = u0 + ub8;
  float bi[8], bfv[8], bg[8], bo[8];
  *(float4*)(bi) = *(const float4*)(p.bias + gu0);
  *(float4*)(bi + 4) = *(const float4*)(p.bias + gu0 + 4);
  *(float4*)(bfv) = *(const float4*)(p.bias + 512 + gu0);
  *(float4*)(bfv + 4) = *(const float4*)(p.bias + 512 + gu0 + 4);
  *(float4*)(bg) = *(const float4*)(p.bias + 1024 + gu0);
  *(float4*)(bg + 4) = *(const float4*)(p.bias + 1024 + gu0 + 4);
  *(float4*)(bo) = *(const float4*)(p.bias + 1536 + gu0);
  *(float4*)(bo + 4) = *(const float4*)(p.bias + 1536 + gu0 + 4);

  float zr[32];
  const float* zrow = zs + erow * 132;
  *(float4*)(zr) = *(const float4*)(zrow + ub8);            // i gate
  *(float4*)(zr + 4) = *(const float4*)(zrow + ub8 + 4);
  *(float4*)(zr + 8) = *(const float4*)(zrow + 32 + ub8);   // f gate
  *(float4*)(zr + 12) = *(const float4*)(zrow + 32 + ub8 + 4);
  *(float4*)(zr + 16) = *(const float4*)(zrow + 64 + ub8);  // g gate
  *(float4*)(zr + 20) = *(const float4*)(zrow + 64 + ub8 + 4);
  *(float4*)(zr + 24) = *(const float4*)(zrow + 96 + ub8);  // o gate
  *(float4*)(zr + 28) = *(const float4*)(zrow + 96 + ub8 + 4);

  const int grow = bm * 128 + erow;
  const size_t gi = (size_t)grow * 512 + gu0;
  float cold[8], cn[8];
  *(float4*)(cold) = *(const float4*)(p.C + gi);
  *(float4*)(cold + 4) = *(const float4*)(p.C + gi + 4);
  unsigned short hv[8];
#pragma unroll
  for (int jj = 0; jj < 8; ++jj) {
    float zi = zr[jj] + bi[jj];
    float zf = zr[8 + jj] + bfv[jj];
    float zg = zr[16 + jj] + bg[jj];
    float zo = zr[24 + jj] + bo[jj];
    float c = sigf(zf) * cold[jj] + sigf(zi) * tanh_f(zg);
    float h = sigf(zo) * tanh_f(c);
    cn[jj] = c;
    bf16 hb = __float2bfloat16(h);
    hv[jj] = *(unsigned short*)&hb;
  }
  *(float4*)(p.C + gi) = make_float4(cn[0], cn[1], cn[2], cn[3]);
  *(float4*)(p.C + gi + 4) = make_float4(cn[4], cn[5], cn[6], cn[7]);
  *(ushort8v*)(p.H + gi) = (ushort8v){hv[0], hv[1], hv[2], hv[3], hv[4], hv[5], hv[6], hv[7]};
}

// out[b] = sigmoid(h2[b,:] @ Wout + bout); one wave per row
__global__ void output_kernel(const bf16* __restrict__ H2, const float* __restrict__ Wout,
                              const float* __restrict__ bout, float* __restrict__ out) {
  int w = threadIdx.x >> 6, l = threadIdx.x & 63;
  int row = blockIdx.x * 4 + w;
  const bf16* h = H2 + (size_t)row * 512;
  float s = 0.f;
#pragma unroll
  for (int k = 0; k < 8; ++k) {
    int kk = l + k * 64;
    s += __bfloat162float(h[kk]) * Wout[kk];
  }
#pragma unroll
  for (int off = 32; off > 0; off >>= 1) s += __shfl_down(s, off);
  if (l == 0) out[row] = sigf(s + bout[0]);
}

extern "C" void kernel_launch(void* const* d_in, const int* in_sizes, int n_in,
                              void* d_out, int out_size, void* d_ws, size_t ws_size,
                              hipStream_t stream) {
  const int* tokens = (const int*)d_in[0];
  const float* emb = (const float*)d_in[1];
  const float* W1 = (const float*)d_in[2];
  const float* U1 = (const float*)d_in[3];
  const float* b1 = (const float*)d_in[4];
  const float* W2 = (const float*)d_in[5];
  const float* U2 = (const float*)d_in[6];
  const float* b2 = (const float*)d_in[7];
  const float* Wout = (const float*)d_in[8];
  const float* bout = (const float*)d_in[9];
  float* out = (float*)d_out;
  char* ws = (char*)d_ws;

  const size_t oXP = 0;          // 80*1024*128 bf16 = 20971520
  const size_t oW1T = 20971520;  // 2048*128 bf16
  const size_t oU1T = 21495808;  // 2048*512 bf16
  const size_t oW2T = 23592960;
  const size_t oU2T = 25690112;
  const size_t oH1 = 27787264;   // 2 x 1024*512 bf16
  const size_t oH2 = 29884416;
  const size_t oC1 = 31981568;   // 1024*512 f32
  const size_t oC2 = 34078720;
  if (ws_size < 36175872) return;

  bf16* XP = (bf16*)(ws + oXP);
  bf16* W1T = (bf16*)(ws + oW1T);
  bf16* U1T = (bf16*)(ws + oU1T);
  bf16* W2T = (bf16*)(ws + oW2T);
  bf16* U2T = (bf16*)(ws + oU2T);
  bf16* H1 = (bf16*)(ws + oH1);
  bf16* H2 = (bf16*)(ws + oH2);
  float* C1 = (float*)(ws + oC1);
  float* C2 = (float*)(ws + oC2);

  hipMemsetAsync(ws + oH1, 0, 1048576, stream);  // H1 buf0
  hipMemsetAsync(ws + oH2, 0, 1048576, stream);  // H2 buf0
  hipMemsetAsync(ws + oC1, 0, 4194304, stream);  // C1 + C2

  embed_kernel<<<5120, 256, 0, stream>>>(tokens, emb, XP);
  transpose_kernel<<<dim3(64, 4), 256, 0, stream>>>(W1, W1T, 100, 128);
  transpose_kernel<<<dim3(64, 16), 256, 0, stream>>>(U1, U1T, 512, 512);
  transpose_kernel<<<dim3(64, 16), 256, 0, stream>>>(W2, W2T, 512, 512);
  transpose_kernel<<<dim3(64, 16), 256, 0, stream>>>(U2, U2T, 512, 512);

  auto mkL1 = [&](int t) {
    CellParams p;
    p.A0 = XP + (size_t)t * 131072; p.B0 = W1T; p.lda0 = 128; p.ldb0 = 128; p.nkt0 = 2;
    p.A1 = H1 + (size_t)(t & 1) * 524288; p.B1 = U1T; p.lda1 = 512; p.ldb1 = 512; p.nkt1 = 8;
    p.bias = b1; p.C = C1; p.H = H1 + (size_t)((t + 1) & 1) * 524288;
    return p;
  };
  auto mkL2 = [&](int t) {
    CellParams p;
    p.A0 = H1 + (size_t)((t + 1) & 1) * 524288; p.B0 = W2T; p.lda0 = 512; p.ldb0 = 512; p.nkt0 = 8;
    p.A1 = H2 + (size_t)(t & 1) * 524288; p.B1 = U2T; p.lda1 = 512; p.ldb1 = 512; p.nkt1 = 8;
    p.bias = b2; p.C = C2; p.H = H2 + (size_t)((t + 1) & 1) * 524288;
    return p;
  };

  cell_kernel<<<128, 512, 0, stream>>>(mkL1(0), mkL1(0));
  for (int k = 1; k < T_; ++k)
    cell_kernel<<<256, 512, 0, stream>>>(mkL2(k - 1), mkL1(k));  // layer2(k-1) || layer1(k)
  cell_kernel<<<128, 512, 0, stream>>>(mkL2(T_ - 1), mkL2(T_ - 1));

  // final h2 in buffer (T_&1)==0
  output_kernel<<<256, 256, 0, stream>>>(H2, Wout, bout, out);
}